// Round 5
// baseline (135075.610 us; speedup 1.0000x reference)
//
#include <hip/hip_runtime.h>

#define T_STEPS 65536
#define IN_DIM 5
#define H1 26
#define H2 121

__device__ __forceinline__ float fsig(float x) {
    float e = __builtin_amdgcn_exp2f(-1.44269504f * x);
    return __builtin_amdgcn_rcpf(1.0f + e);
}
__device__ __forceinline__ float ftanh(float x) {
    float e = __builtin_amdgcn_exp2f(2.88539008f * x);
    return 1.0f - 2.0f * __builtin_amdgcn_rcpf(e + 1.0f);
}

#define FOR16(F) F(0) F(1) F(2) F(3) F(4) F(5) F(6) F(7) F(8) F(9) F(10) F(11) F(12) F(13) F(14) F(15)
#define FOR64(F) F(0) F(1) F(2) F(3) F(4) F(5) F(6) F(7) F(8) F(9) F(10) F(11) F(12) F(13) F(14) F(15) \
                 F(16) F(17) F(18) F(19) F(20) F(21) F(22) F(23) F(24) F(25) F(26) F(27) F(28) F(29) F(30) F(31) \
                 F(32) F(33) F(34) F(35) F(36) F(37) F(38) F(39) F(40) F(41) F(42) F(43) F(44) F(45) F(46) F(47) \
                 F(48) F(49) F(50) F(51) F(52) F(53) F(54) F(55) F(56) F(57) F(58) F(59) F(60) F(61) F(62) F(63)
#define FOR57(F) F(0) F(1) F(2) F(3) F(4) F(5) F(6) F(7) F(8) F(9) F(10) F(11) F(12) F(13) F(14) F(15) \
                 F(16) F(17) F(18) F(19) F(20) F(21) F(22) F(23) F(24) F(25) F(26) F(27) F(28) F(29) F(30) F(31) \
                 F(32) F(33) F(34) F(35) F(36) F(37) F(38) F(39) F(40) F(41) F(42) F(43) F(44) F(45) F(46) F(47) \
                 F(48) F(49) F(50) F(51) F(52) F(53) F(54) F(55) F(56)
#define FOR7T(F) F(57) F(58) F(59) F(60) F(61) F(62) F(63)
#define FOR10(F) F(0) F(1) F(2) F(3) F(4) F(5) F(6) F(7) F(8) F(9)
#define FOR6T(F) F(10) F(11) F(12) F(13) F(14) F(15)
#define FOR26(F) F(0) F(1) F(2) F(3) F(4) F(5) F(6) F(7) F(8) F(9) F(10) F(11) F(12) F(13) F(14) F(15) \
                 F(16) F(17) F(18) F(19) F(20) F(21) F(22) F(23) F(24) F(25)

// One persistent workgroup. 1024 threads = 16 waves = 4 waves/EU (VGPR cap 128).
//
// R1-R4 failure analysis: three different register formulations all produced
// identical perf (VGPR~60-64, FETCH~1.7GB = 26KB/step ~ 6.6 floats/thread/step).
// Diagnosis: MachineSink moves the (readonly, __restrict__) weight loads INTO
// the loop body; per-step re-reads are served by L1/L2, FETCH shows the miss
// residue. Fix: asm volatile("" : "+v"(w)) pins — an opaque register def that
// cannot be sunk, duplicated, or rematerialized, forcing VGPR residency.
//
// threads 0..959       : gates2 rows 0..479, 2 threads/row (half=tid&1)
// wave 15 lanes 0..51  : LSTM1 (rows l, l+52), act by lanes<26 (intra-wave only)
// wave 15 lanes 52..59 : gates2 rows 480..483 (2 threads/row)
// wave 15 lane 60      : y-store of previous step
// threads 0..127       : h2/c2 activation + y butterfly reduce (after B2)
__global__ __attribute__((amdgpu_flat_work_group_size(1024, 1024)))
__attribute__((amdgpu_waves_per_eu(4, 4)))
void lstm_seq_kernel(
    const float* __restrict__ x,
    const float* __restrict__ W_ih1, const float* __restrict__ W_hh1,
    const float* __restrict__ b_ih1, const float* __restrict__ b_hh1,
    const float* __restrict__ W_ih2, const float* __restrict__ W_hh2,
    const float* __restrict__ b_ih2, const float* __restrict__ b_hh2,
    const float* __restrict__ W_lin, const float* __restrict__ b_lin,
    const float* __restrict__ h1_0, const float* __restrict__ c1_0,
    const float* __restrict__ h2_0, const float* __restrict__ c2_0,
    float* __restrict__ out)
{
    __shared__ __align__(16) float h1_lds[32];    // 26 + zero pad
    __shared__ __align__(16) float h2_lds[128];   // 121 + zero pad
    __shared__ float g1_lds[104];
    __shared__ float g2_lds[484];
    __shared__ float ypart[2];

    const int tid = threadIdx.x;
    const int lane15 = tid - 960;                 // valid when tid>=960
    const bool in_w15 = (tid >= 960);
    const bool is_g2 = (tid < 960) || (lane15 >= 52 && lane15 < 60);
    const int row  = (tid < 960) ? (tid >> 1) : (480 + ((tid - 1012) >> 1));
    const int half = tid & 1;

    // ---- named scalar weight registers ----
#define DECW(i) float w##i = 0.0f;
    FOR64(DECW)
#define DECU(i) float u##i = 0.0f;
    FOR16(DECU)

    float c2 = 0.0f, wlin = 0.0f, accbias = 0.0f;
    float px0 = 0.0f, px1 = 0.0f, px2 = 0.0f, px3 = 0.0f, px4 = 0.0f;

    if (is_g2) {
        const float* wp = W_hh2 + row * H2 + half * 64;
        const float* up = W_ih2 + row * H1 + half * 16;
        // k = half*64 + m : m<57 always valid (half=1 -> k<=120)
#define LDW(m) w##m = wp[m];
        FOR57(LDW)
#define LDU(m) u##m = up[m];
        FOR10(LDU)
        if (half == 0) {   // tail only valid for half 0 (avoids OOB speculation)
#define LDW2(m) w##m = wp[m];
            FOR7T(LDW2)
#define LDU2(m) u##m = up[m];
            FOR6T(LDU2)
            accbias = b_ih2[row] + b_hh2[row];
        }
    } else if (lane15 < 52) {
        const int r0 = lane15, r1 = lane15 + 52;
#define LD1A(k) w##k = W_hh1[r0 * H1 + k];
        FOR26(LD1A)
#define LD1B(a,b) w##b = W_hh1[r1 * H1 + a];
        LD1B(0,32) LD1B(1,33) LD1B(2,34) LD1B(3,35) LD1B(4,36) LD1B(5,37)
        LD1B(6,38) LD1B(7,39) LD1B(8,40) LD1B(9,41) LD1B(10,42) LD1B(11,43)
        LD1B(12,44) LD1B(13,45) LD1B(14,46) LD1B(15,47) LD1B(16,48) LD1B(17,49)
        LD1B(18,50) LD1B(19,51) LD1B(20,52) LD1B(21,53) LD1B(22,54) LD1B(23,55)
        LD1B(24,56) LD1B(25,57)
        u0 = W_ih1[r0 * 5 + 0]; u1 = W_ih1[r0 * 5 + 1]; u2 = W_ih1[r0 * 5 + 2];
        u3 = W_ih1[r0 * 5 + 3]; u4 = W_ih1[r0 * 5 + 4];
        u5 = W_ih1[r1 * 5 + 0]; u6 = W_ih1[r1 * 5 + 1]; u7 = W_ih1[r1 * 5 + 2];
        u8 = W_ih1[r1 * 5 + 3]; u9 = W_ih1[r1 * 5 + 4];
        u10 = b_ih1[r0] + b_hh1[r0];
        u11 = b_ih1[r1] + b_hh1[r1];
        if (lane15 < H1) u12 = c1_0[lane15];
        px0 = x[0]; px1 = x[1]; px2 = x[2]; px3 = x[3]; px4 = x[4];
    }
    if (tid < H2) { c2 = c2_0[tid]; wlin = W_lin[tid]; }

    // ---- PIN: opaque register barrier. After this, every weight's only
    // reaching definition is an asm VGPR output — unsinkable, unrematable. ----
#define PIN(v) asm volatile("" : "+v"(v));
#define PINW(i) PIN(w##i)
    FOR64(PINW)
#define PINU(i) PIN(u##i)
    FOR16(PINU)
    PIN(accbias) PIN(c2) PIN(wlin)

    if (tid < 32)  h1_lds[tid] = (tid < H1) ? h1_0[tid] : 0.0f;
    if (tid < 128) h2_lds[tid] = (tid < H2) ? h2_0[tid] : 0.0f;
    const float blin = b_lin[0];
    __syncthreads();

    const float4* h2v4 = reinterpret_cast<const float4*>(h2_lds);
    const float4* h1v4 = reinterpret_cast<const float4*>(h1_lds);

    float acc = 0.0f;

    for (int t = 0; t < T_STEPS; ++t) {
        // ---------------- Phase A: W_hh2 @ h2(t-1), LSTM1, y-store ----------
        if (is_g2) {
            acc = accbias;
#define PHA(q,a,b,c,d) { float4 h = h2v4[half * 16 + q]; \
            acc = fmaf(w##a, h.x, acc); acc = fmaf(w##b, h.y, acc); \
            acc = fmaf(w##c, h.z, acc); acc = fmaf(w##d, h.w, acc); }
            PHA(0,0,1,2,3)     PHA(1,4,5,6,7)     PHA(2,8,9,10,11)    PHA(3,12,13,14,15)
            PHA(4,16,17,18,19) PHA(5,20,21,22,23) PHA(6,24,25,26,27)  PHA(7,28,29,30,31)
            PHA(8,32,33,34,35) PHA(9,36,37,38,39) PHA(10,40,41,42,43) PHA(11,44,45,46,47)
            PHA(12,48,49,50,51) PHA(13,52,53,54,55) PHA(14,56,57,58,59) PHA(15,60,61,62,63)
        }
        if (in_w15) {
            if (lane15 < 52) {
                float g0 = u10, g1v = u11;
                g0  = fmaf(u0, px0, g0);  g0  = fmaf(u1, px1, g0);  g0  = fmaf(u2, px2, g0);
                g0  = fmaf(u3, px3, g0);  g0  = fmaf(u4, px4, g0);
                g1v = fmaf(u5, px0, g1v); g1v = fmaf(u6, px1, g1v); g1v = fmaf(u7, px2, g1v);
                g1v = fmaf(u8, px3, g1v); g1v = fmaf(u9, px4, g1v);
                // prefetch x(t+1): latency hides under rest of the step
                {
                    const int tn = (t + 1 < T_STEPS) ? (t + 1) : t;
                    const float* xn = x + tn * IN_DIM;
                    px0 = xn[0]; px1 = xn[1]; px2 = xn[2]; px3 = xn[3]; px4 = xn[4];
                }
#define PH1(q,a0,a1,a2,a3,b0,b1,b2,b3) { float4 h = h1v4[q]; \
                g0  = fmaf(w##a0, h.x, g0);  g0  = fmaf(w##a1, h.y, g0); \
                g0  = fmaf(w##a2, h.z, g0);  g0  = fmaf(w##a3, h.w, g0); \
                g1v = fmaf(w##b0, h.x, g1v); g1v = fmaf(w##b1, h.y, g1v); \
                g1v = fmaf(w##b2, h.z, g1v); g1v = fmaf(w##b3, h.w, g1v); }
                PH1(0, 0,1,2,3,     32,33,34,35)
                PH1(1, 4,5,6,7,     36,37,38,39)
                PH1(2, 8,9,10,11,   40,41,42,43)
                PH1(3, 12,13,14,15, 44,45,46,47)
                PH1(4, 16,17,18,19, 48,49,50,51)
                PH1(5, 20,21,22,23, 52,53,54,55)
                PH1(6, 24,25,26,27, 56,57,58,59)
                PH1(7, 28,29,30,31, 60,61,62,63)
                g1_lds[lane15]      = g0;
                g1_lds[lane15 + 52] = g1v;
                asm volatile("s_waitcnt lgkmcnt(0)" ::: "memory");
                if (lane15 < H1) {
                    float gi = g1_lds[lane15];
                    float gf = g1_lds[H1 + lane15];
                    float gg = g1_lds[2 * H1 + lane15];
                    float go = g1_lds[3 * H1 + lane15];
                    float c1 = u12;
                    c1 = fsig(gf) * c1 + fsig(gi) * ftanh(gg);
                    u12 = c1;
                    h1_lds[lane15] = fsig(go) * ftanh(c1);
                }
            } else if (lane15 == 60) {
                if (t > 0) out[t - 1] = ypart[0] + ypart[1] + blin;
            }
        }
        __syncthreads();  // B1: h1(t) visible

        // ---------------- Phase C: += W_ih2 @ h1(t), combine halves ---------
        if (is_g2) {
#define PHC(q,a,b,c,d) { float4 h = h1v4[half * 4 + q]; \
            acc = fmaf(u##a, h.x, acc); acc = fmaf(u##b, h.y, acc); \
            acc = fmaf(u##c, h.z, acc); acc = fmaf(u##d, h.w, acc); }
            PHC(0,0,1,2,3) PHC(1,4,5,6,7) PHC(2,8,9,10,11) PHC(3,12,13,14,15)
            acc += __shfl_xor(acc, 1);
            if (half == 0) g2_lds[row] = acc;
        }
        __syncthreads();  // B2: gates2 visible

        // ---------------- Act: c2/h2 update + y partial reduce --------------
        if (tid < 128) {
            float p = 0.0f;
            if (tid < H2) {
                float gi = g2_lds[tid];
                float gf = g2_lds[H2 + tid];
                float gg = g2_lds[2 * H2 + tid];
                float go = g2_lds[3 * H2 + tid];
                c2 = fsig(gf) * c2 + fsig(gi) * ftanh(gg);
                float h2n = fsig(go) * ftanh(c2);
                h2_lds[tid] = h2n;
                p = h2n * wlin;
            }
            #pragma unroll
            for (int off = 32; off >= 1; off >>= 1)
                p += __shfl_xor(p, off);
            if ((tid & 63) == 0) ypart[tid >> 6] = p;
        }
        __syncthreads();  // B3: h2(t), ypart visible
    }

    if (tid == 1020) out[T_STEPS - 1] = ypart[0] + ypart[1] + blin;
}

extern "C" void kernel_launch(void* const* d_in, const int* in_sizes, int n_in,
                              void* d_out, int out_size, void* d_ws, size_t ws_size,
                              hipStream_t stream) {
    const float* x     = (const float*)d_in[0];
    const float* W_ih1 = (const float*)d_in[1];
    const float* W_hh1 = (const float*)d_in[2];
    const float* b_ih1 = (const float*)d_in[3];
    const float* b_hh1 = (const float*)d_in[4];
    const float* W_ih2 = (const float*)d_in[5];
    const float* W_hh2 = (const float*)d_in[6];
    const float* b_ih2 = (const float*)d_in[7];
    const float* b_hh2 = (const float*)d_in[8];
    const float* W_lin = (const float*)d_in[9];
    const float* b_lin = (const float*)d_in[10];
    const float* h1_0  = (const float*)d_in[11];
    const float* c1_0  = (const float*)d_in[12];
    const float* h2_0  = (const float*)d_in[13];
    const float* c2_0  = (const float*)d_in[14];
    float* out = (float*)d_out;

    hipLaunchKernelGGL(lstm_seq_kernel, dim3(1), dim3(1024), 0, stream,
                       x, W_ih1, W_hh1, b_ih1, b_hh1,
                       W_ih2, W_hh2, b_ih2, b_hh2,
                       W_lin, b_lin, h1_0, c1_0, h2_0, c2_0, out);
}

// Round 6
// 106687.256 us; speedup vs baseline: 1.2661x; 1.2661x over previous
//
#include <hip/hip_runtime.h>

#define T_STEPS 65536
#define IN_DIM 5
#define H1 26
#define H2 121

__device__ __forceinline__ float fsig(float x) {
    float e = __builtin_amdgcn_exp2f(-1.44269504f * x);
    return __builtin_amdgcn_rcpf(1.0f + e);
}
__device__ __forceinline__ float ftanh(float x) {
    float e = __builtin_amdgcn_exp2f(2.88539008f * x);
    return 1.0f - 2.0f * __builtin_amdgcn_rcpf(e + 1.0f);
}

// 121 w-registers, 28 v-registers (names shared across thread roles)
#define FORW(F) F(0) F(1) F(2) F(3) F(4) F(5) F(6) F(7) F(8) F(9) F(10) F(11) F(12) F(13) F(14) F(15) \
 F(16) F(17) F(18) F(19) F(20) F(21) F(22) F(23) F(24) F(25) F(26) F(27) F(28) F(29) F(30) F(31) \
 F(32) F(33) F(34) F(35) F(36) F(37) F(38) F(39) F(40) F(41) F(42) F(43) F(44) F(45) F(46) F(47) \
 F(48) F(49) F(50) F(51) F(52) F(53) F(54) F(55) F(56) F(57) F(58) F(59) F(60) F(61) F(62) F(63) \
 F(64) F(65) F(66) F(67) F(68) F(69) F(70) F(71) F(72) F(73) F(74) F(75) F(76) F(77) F(78) F(79) \
 F(80) F(81) F(82) F(83) F(84) F(85) F(86) F(87) F(88) F(89) F(90) F(91) F(92) F(93) F(94) F(95) \
 F(96) F(97) F(98) F(99) F(100) F(101) F(102) F(103) F(104) F(105) F(106) F(107) F(108) F(109) F(110) F(111) \
 F(112) F(113) F(114) F(115) F(116) F(117) F(118) F(119) F(120)
#define FORV(F) F(0) F(1) F(2) F(3) F(4) F(5) F(6) F(7) F(8) F(9) F(10) F(11) F(12) F(13) \
 F(14) F(15) F(16) F(17) F(18) F(19) F(20) F(21) F(22) F(23) F(24) F(25) F(26) F(27)
#define FOR26(F) F(0) F(1) F(2) F(3) F(4) F(5) F(6) F(7) F(8) F(9) F(10) F(11) F(12) F(13) \
 F(14) F(15) F(16) F(17) F(18) F(19) F(20) F(21) F(22) F(23) F(24) F(25)
// (src_index, dst_reg) pairs for LSTM1 gate blocks f,g,o
#define L2L(F) F(0,26) F(1,27) F(2,28) F(3,29) F(4,30) F(5,31) F(6,32) F(7,33) F(8,34) F(9,35) \
 F(10,36) F(11,37) F(12,38) F(13,39) F(14,40) F(15,41) F(16,42) F(17,43) F(18,44) F(19,45) \
 F(20,46) F(21,47) F(22,48) F(23,49) F(24,50) F(25,51)
#define L3L(F) F(0,52) F(1,53) F(2,54) F(3,55) F(4,56) F(5,57) F(6,58) F(7,59) F(8,60) F(9,61) \
 F(10,62) F(11,63) F(12,64) F(13,65) F(14,66) F(15,67) F(16,68) F(17,69) F(18,70) F(19,71) \
 F(20,72) F(21,73) F(22,74) F(23,75) F(24,76) F(25,77)
#define L4L(F) F(0,78) F(1,79) F(2,80) F(3,81) F(4,82) F(5,83) F(6,84) F(7,85) F(8,86) F(9,87) \
 F(10,88) F(11,89) F(12,90) F(13,91) F(14,92) F(15,93) F(16,94) F(17,95) F(18,96) F(19,97) \
 F(20,98) F(21,99) F(22,100) F(23,101) F(24,102) F(25,103)

// 512 threads = 8 waves = 2 waves/SIMD -> architectural VGPR cap 256 (vs the
// 64-cap observed for 1024-thread blocks in R1-R5, where ~75 floats/thread
// went to memory: FETCH 26KB/step, 66% stall). One thread per gates2 row.
//
// tid 0..483   : gates2 row = tid. w0..w120 = W_hh2 row, v0..v25 = W_ih2 row
//                (v26=v27=0), bias; tid<121 also holds c2, wlin + act phase.
// tid 484..509 : LSTM1 unit l=tid-484. Owns ALL 4 gate rows of unit l
//                (i,f,g,o = rows l,26+l,52+l,78+l): w0..w103 = W_hh1 rows,
//                v0..v19 = W_ih1 rows, v20..v23 = biases, v26 = c1.
//                Lane-local c1/h1 update — no LDS gate exchange.
// tid 510      : y-store of previous step.
__global__ __attribute__((amdgpu_flat_work_group_size(512, 512)))
__attribute__((amdgpu_waves_per_eu(2, 2)))
void lstm_seq_kernel(
    const float* __restrict__ x,
    const float* __restrict__ W_ih1, const float* __restrict__ W_hh1,
    const float* __restrict__ b_ih1, const float* __restrict__ b_hh1,
    const float* __restrict__ W_ih2, const float* __restrict__ W_hh2,
    const float* __restrict__ b_ih2, const float* __restrict__ b_hh2,
    const float* __restrict__ W_lin, const float* __restrict__ b_lin,
    const float* __restrict__ h1_0, const float* __restrict__ c1_0,
    const float* __restrict__ h2_0, const float* __restrict__ c2_0,
    float* __restrict__ out)
{
    __shared__ __align__(16) float h1_lds[32];    // 26 + zero pad
    __shared__ __align__(16) float h2_lds[128];   // 121 + zero pad
    __shared__ float g2_lds[484];
    __shared__ float ypart[2];

    const int tid = threadIdx.x;
    const bool is_g2 = (tid < 484);
    const bool is_l1 = (tid >= 484 && tid < 510);

#define DECW(i) float w##i = 0.0f;
    FORW(DECW)
#define DECV(i) float v##i = 0.0f;
    FORV(DECV)

    float c2 = 0.0f, wlin = 0.0f, bias = 0.0f;
    float px0 = 0.0f, px1 = 0.0f, px2 = 0.0f, px3 = 0.0f, px4 = 0.0f;

    if (is_g2) {
        const float* wp = W_hh2 + tid * H2;
        const float* up = W_ih2 + tid * H1;
#define LDW(m) w##m = wp[m];
        FORW(LDW)
#define LDU(m) v##m = up[m];
        FOR26(LDU)
        bias = b_ih2[tid] + b_hh2[tid];
    } else if (is_l1) {
        const int l = tid - 484;
        const float* p1 = W_hh1 + l * H1;           // row l + 676*k strides
#define LA(j) w##j = p1[j];
        FOR26(LA)
#define LB(j,d) w##d = p1[676 + j];
        L2L(LB)
#define LC(j,d) w##d = p1[1352 + j];
        L3L(LC)
#define LDD(j,d) w##d = p1[2028 + j];
        L4L(LDD)
        const float* q1 = W_ih1 + l * IN_DIM;       // row l + 130*k strides
        v0  = q1[0];   v1  = q1[1];   v2  = q1[2];   v3  = q1[3];   v4  = q1[4];
        v5  = q1[130]; v6  = q1[131]; v7  = q1[132]; v8  = q1[133]; v9  = q1[134];
        v10 = q1[260]; v11 = q1[261]; v12 = q1[262]; v13 = q1[263]; v14 = q1[264];
        v15 = q1[390]; v16 = q1[391]; v17 = q1[392]; v18 = q1[393]; v19 = q1[394];
        v20 = b_ih1[l]      + b_hh1[l];
        v21 = b_ih1[26 + l] + b_hh1[26 + l];
        v22 = b_ih1[52 + l] + b_hh1[52 + l];
        v23 = b_ih1[78 + l] + b_hh1[78 + l];
        v26 = c1_0[l];                               // c1 state
        px0 = x[0]; px1 = x[1]; px2 = x[2]; px3 = x[3]; px4 = x[4];
    }
    if (tid < H2) { c2 = c2_0[tid]; wlin = W_lin[tid]; }

    // opaque register barrier on all persistent values
#define PIN(a) asm volatile("" : "+v"(a));
#define PINW(i) PIN(w##i)
    FORW(PINW)
#define PINV(i) PIN(v##i)
    FORV(PINV)
    PIN(bias) PIN(c2) PIN(wlin)

    if (tid < 32)  h1_lds[tid] = (tid < H1) ? h1_0[tid] : 0.0f;
    if (tid < 128) h2_lds[tid] = (tid < H2) ? h2_0[tid] : 0.0f;
    const float blin = b_lin[0];
    __syncthreads();

    const float4* h2v4 = reinterpret_cast<const float4*>(h2_lds);
    const float4* h1v4 = reinterpret_cast<const float4*>(h1_lds);

    float acc = 0.0f;

    for (int t = 0; t < T_STEPS; ++t) {
        // ---------- Phase A: W_hh2 @ h2(t-1)  ||  LSTM1  ||  y-store --------
        if (is_g2) {
            acc = bias;
#define PHA(q,a,b,c,d) { float4 h = h2v4[q]; \
            acc = fmaf(w##a, h.x, acc); acc = fmaf(w##b, h.y, acc); \
            acc = fmaf(w##c, h.z, acc); acc = fmaf(w##d, h.w, acc); }
            PHA(0,0,1,2,3)      PHA(1,4,5,6,7)      PHA(2,8,9,10,11)
            PHA(3,12,13,14,15)  PHA(4,16,17,18,19)  PHA(5,20,21,22,23)
            PHA(6,24,25,26,27)  PHA(7,28,29,30,31)  PHA(8,32,33,34,35)
            PHA(9,36,37,38,39)
            __builtin_amdgcn_sched_barrier(0);
            PHA(10,40,41,42,43) PHA(11,44,45,46,47) PHA(12,48,49,50,51)
            PHA(13,52,53,54,55) PHA(14,56,57,58,59) PHA(15,60,61,62,63)
            PHA(16,64,65,66,67) PHA(17,68,69,70,71) PHA(18,72,73,74,75)
            PHA(19,76,77,78,79)
            __builtin_amdgcn_sched_barrier(0);
            PHA(20,80,81,82,83) PHA(21,84,85,86,87) PHA(22,88,89,90,91)
            PHA(23,92,93,94,95) PHA(24,96,97,98,99) PHA(25,100,101,102,103)
            PHA(26,104,105,106,107) PHA(27,108,109,110,111)
            PHA(28,112,113,114,115) PHA(29,116,117,118,119)
            acc = fmaf(w120, h2_lds[120], acc);
        } else if (is_l1) {
            float ga0 = v20, ga1 = v21, ga2 = v22, ga3 = v23;
            ga0 = fmaf(v0,  px0, ga0); ga0 = fmaf(v1,  px1, ga0); ga0 = fmaf(v2,  px2, ga0);
            ga0 = fmaf(v3,  px3, ga0); ga0 = fmaf(v4,  px4, ga0);
            ga1 = fmaf(v5,  px0, ga1); ga1 = fmaf(v6,  px1, ga1); ga1 = fmaf(v7,  px2, ga1);
            ga1 = fmaf(v8,  px3, ga1); ga1 = fmaf(v9,  px4, ga1);
            ga2 = fmaf(v10, px0, ga2); ga2 = fmaf(v11, px1, ga2); ga2 = fmaf(v12, px2, ga2);
            ga2 = fmaf(v13, px3, ga2); ga2 = fmaf(v14, px4, ga2);
            ga3 = fmaf(v15, px0, ga3); ga3 = fmaf(v16, px1, ga3); ga3 = fmaf(v17, px2, ga3);
            ga3 = fmaf(v18, px3, ga3); ga3 = fmaf(v19, px4, ga3);
            {   // prefetch x(t+1)
                const int tn = (t + 1 < T_STEPS) ? (t + 1) : t;
                const float* xn = x + tn * IN_DIM;
                px0 = xn[0]; px1 = xn[1]; px2 = xn[2]; px3 = xn[3]; px4 = xn[4];
            }
#define G4(q,a0,a1,a2,a3,b0,b1,b2,b3,c0,c1n,c2n,c3,d0,d1,d2,d3) { float4 h = h1v4[q]; \
            ga0 = fmaf(w##a0, h.x, ga0); ga0 = fmaf(w##a1, h.y, ga0); \
            ga0 = fmaf(w##a2, h.z, ga0); ga0 = fmaf(w##a3, h.w, ga0); \
            ga1 = fmaf(w##b0, h.x, ga1); ga1 = fmaf(w##b1, h.y, ga1); \
            ga1 = fmaf(w##b2, h.z, ga1); ga1 = fmaf(w##b3, h.w, ga1); \
            ga2 = fmaf(w##c0, h.x, ga2); ga2 = fmaf(w##c1n, h.y, ga2); \
            ga2 = fmaf(w##c2n, h.z, ga2); ga2 = fmaf(w##c3, h.w, ga2); \
            ga3 = fmaf(w##d0, h.x, ga3); ga3 = fmaf(w##d1, h.y, ga3); \
            ga3 = fmaf(w##d2, h.z, ga3); ga3 = fmaf(w##d3, h.w, ga3); }
            G4(0, 0,1,2,3,     26,27,28,29, 52,53,54,55, 78,79,80,81)
            G4(1, 4,5,6,7,     30,31,32,33, 56,57,58,59, 82,83,84,85)
            G4(2, 8,9,10,11,   34,35,36,37, 60,61,62,63, 86,87,88,89)
            G4(3, 12,13,14,15, 38,39,40,41, 64,65,66,67, 90,91,92,93)
            G4(4, 16,17,18,19, 42,43,44,45, 68,69,70,71, 94,95,96,97)
            G4(5, 20,21,22,23, 46,47,48,49, 72,73,74,75, 98,99,100,101)
            {   // tail: h1[24], h1[25]
                float4 h = h1v4[6];
                ga0 = fmaf(w24,  h.x, ga0); ga0 = fmaf(w25,  h.y, ga0);
                ga1 = fmaf(w50,  h.x, ga1); ga1 = fmaf(w51,  h.y, ga1);
                ga2 = fmaf(w76,  h.x, ga2); ga2 = fmaf(w77,  h.y, ga2);
                ga3 = fmaf(w102, h.x, ga3); ga3 = fmaf(w103, h.y, ga3);
            }
            float c1 = v26;
            c1 = fsig(ga1) * c1 + fsig(ga0) * ftanh(ga2);
            v26 = c1;
            h1_lds[tid - 484] = fsig(ga3) * ftanh(c1);
        } else if (tid == 510) {
            if (t > 0) out[t - 1] = ypart[0] + ypart[1] + blin;
        }
        __syncthreads();  // B1: h1(t) visible

        // ---------- Phase C: += W_ih2 @ h1(t), write gate ------------------
        if (is_g2) {
#define PHC(q,a,b,c,d) { float4 h = h1v4[q]; \
            acc = fmaf(v##a, h.x, acc); acc = fmaf(v##b, h.y, acc); \
            acc = fmaf(v##c, h.z, acc); acc = fmaf(v##d, h.w, acc); }
            PHC(0,0,1,2,3)     PHC(1,4,5,6,7)     PHC(2,8,9,10,11)
            PHC(3,12,13,14,15) PHC(4,16,17,18,19) PHC(5,20,21,22,23)
            PHC(6,24,25,26,27)
            g2_lds[tid] = acc;
        }
        __syncthreads();  // B2: gates visible

        // ---------- Act: c2/h2 update + y partial reduce -------------------
        if (tid < 128) {
            float p = 0.0f;
            if (tid < H2) {
                float gi = g2_lds[tid];
                float gf = g2_lds[121 + tid];
                float gg = g2_lds[242 + tid];
                float go = g2_lds[363 + tid];
                c2 = fsig(gf) * c2 + fsig(gi) * ftanh(gg);
                float h2n = fsig(go) * ftanh(c2);
                h2_lds[tid] = h2n;
                p = h2n * wlin;
            }
            #pragma unroll
            for (int off = 32; off >= 1; off >>= 1)
                p += __shfl_xor(p, off);
            if ((tid & 63) == 0) ypart[tid >> 6] = p;
        }
        __syncthreads();  // B3: h2(t), ypart visible
    }

    if (tid == 510) out[T_STEPS - 1] = ypart[0] + ypart[1] + blin;
}

extern "C" void kernel_launch(void* const* d_in, const int* in_sizes, int n_in,
                              void* d_out, int out_size, void* d_ws, size_t ws_size,
                              hipStream_t stream) {
    const float* x     = (const float*)d_in[0];
    const float* W_ih1 = (const float*)d_in[1];
    const float* W_hh1 = (const float*)d_in[2];
    const float* b_ih1 = (const float*)d_in[3];
    const float* b_hh1 = (const float*)d_in[4];
    const float* W_ih2 = (const float*)d_in[5];
    const float* W_hh2 = (const float*)d_in[6];
    const float* b_ih2 = (const float*)d_in[7];
    const float* b_hh2 = (const float*)d_in[8];
    const float* W_lin = (const float*)d_in[9];
    const float* b_lin = (const float*)d_in[10];
    const float* h1_0  = (const float*)d_in[11];
    const float* c1_0  = (const float*)d_in[12];
    const float* h2_0  = (const float*)d_in[13];
    const float* c2_0  = (const float*)d_in[14];
    float* out = (float*)d_out;

    hipLaunchKernelGGL(lstm_seq_kernel, dim3(1), dim3(512), 0, stream,
                       x, W_ih1, W_hh1, b_ih1, b_hh1,
                       W_ih2, W_hh2, b_ih2, b_hh2,
                       W_lin, b_lin, h1_0, c1_0, h2_0, c2_0, out);
}